// Round 2
// baseline (481.428 us; speedup 1.0000x reference)
//
#include <hip/hip_runtime.h>
#include <hip/hip_bf16.h>

#define NB 4
#define SEQ 2048
#define DMODEL 512
#define HEADS 8
#define HDIM 64
#define QKSCALE 0.125f

typedef __bf16 bf16_t;
typedef bf16_t bf16x8 __attribute__((ext_vector_type(8)));
typedef bf16_t bf16x4 __attribute__((ext_vector_type(4)));
typedef float f32x4 __attribute__((ext_vector_type(4)));

// XOR swizzle: rows are 64 bf16 = 128 B = 8x16B slots; spread column-slot by row&7.
__device__ __forceinline__ int swz(int row, int c16) {
    return (row << 7) + (((c16) ^ (row & 7)) << 4);
}

__device__ __forceinline__ bf16x4 cvt4(float4 v) {
    bf16x4 r;
    r[0] = (bf16_t)v.x; r[1] = (bf16_t)v.y; r[2] = (bf16_t)v.z; r[3] = (bf16_t)v.w;
    return r;
}

// ---------------------------------------------------------------------------
// K0: transpose + convert the 5 weight matrices (512x512 fp32 [k][n]) into
//     bf16 [n][k] so GEMM B-fragments are contiguous along k.
// grid: 5 * 64 tiles of 64x64, 256 threads
// ---------------------------------------------------------------------------
__global__ __launch_bounds__(256) void prep_weights(
    const float* __restrict__ Wq, const float* __restrict__ Wk,
    const float* __restrict__ Wv, const float* __restrict__ Wg,
    const float* __restrict__ Wo, bf16_t* __restrict__ out)
{
    __shared__ float t[64][65];
    const int m  = blockIdx.x >> 6;
    const int t2 = blockIdx.x & 63;
    const int tr = t2 >> 3, tc = t2 & 7;   // tr: k-tile, tc: n-tile
    const float* W = (m == 0) ? Wq : (m == 1) ? Wk : (m == 2) ? Wv : (m == 3) ? Wg : Wo;
    const int r0 = threadIdx.x >> 6;  // 0..3
    const int c  = threadIdx.x & 63;
#pragma unroll
    for (int i = 0; i < 64; i += 4) {
        int row = i + r0;
        t[row][c] = W[(size_t)(tr * 64 + row) * DMODEL + tc * 64 + c];
    }
    __syncthreads();
    bf16_t* o = out + (size_t)m * (DMODEL * DMODEL);
#pragma unroll
    for (int i = 0; i < 64; i += 4) {
        int row = i + r0;
        o[(size_t)(tc * 64 + row) * DMODEL + tr * 64 + c] = (bf16_t)t[c][row];
    }
}

// ---------------------------------------------------------------------------
// K1: projection GEMM  (M=8192, N=512, K=512), A fp32, Wt bf16 [n][k]
// MODE 0: out bf16 row-major, val=(acc+bias)*scale
// MODE 1: out bf16 transposed -> (B, H, HDIM, SEQ)  (for wv)
// MODE 2: out bf16 row-major, sigmoid(acc+bias)     (for g)
// tiles 64x64, BK=64, 4 waves, grid 128*8=1024
// ---------------------------------------------------------------------------
template <int MODE>
__global__ __launch_bounds__(256) void gemm_proj(
    const float* __restrict__ A, const bf16_t* __restrict__ Wt,
    const float* __restrict__ bias, void* __restrict__ out, float scale)
{
    __shared__ __align__(16) char smA[8192];
    __shared__ __align__(16) char smB[8192];
    const int tid = threadIdx.x;
    const int lane = tid & 63, w = tid >> 6;
    const int m0 = (blockIdx.x >> 3) << 6;
    const int n0 = (blockIdx.x & 7) << 6;
    const int wrow = (w >> 1) * 32, wcol = (w & 1) * 32;
    const int lr = lane & 15, lg = lane >> 4;

    f32x4 acc[2][2] = {};
    for (int kb = 0; kb < 8; ++kb) {
        const int k0 = kb * 64;
        __syncthreads();
#pragma unroll
        for (int i = 0; i < 4; ++i) {
            int f = tid + i * 256;
            int row = f >> 4, c4 = f & 15;
            float4 v = *(const float4*)(A + (size_t)(m0 + row) * DMODEL + k0 + c4 * 4);
            *(bf16x4*)(smA + swz(row, c4 >> 1) + ((c4 & 1) << 3)) = cvt4(v);
        }
#pragma unroll
        for (int i = 0; i < 2; ++i) {
            int f = tid + i * 256;
            int row = f >> 3, c16 = f & 7;
            uint4 v = *(const uint4*)(Wt + (size_t)(n0 + row) * DMODEL + k0 + c16 * 8);
            *(uint4*)(smB + swz(row, c16)) = v;
        }
        __syncthreads();
#pragma unroll
        for (int ks = 0; ks < 2; ++ks) {
            bf16x8 a[2], b[2];
#pragma unroll
            for (int mi = 0; mi < 2; ++mi)
                a[mi] = *(const bf16x8*)(smA + swz(wrow + mi * 16 + lr, lg + ks * 4));
#pragma unroll
            for (int ni = 0; ni < 2; ++ni)
                b[ni] = *(const bf16x8*)(smB + swz(wcol + ni * 16 + lr, lg + ks * 4));
#pragma unroll
            for (int mi = 0; mi < 2; ++mi)
#pragma unroll
                for (int ni = 0; ni < 2; ++ni)
                    acc[mi][ni] = __builtin_amdgcn_mfma_f32_16x16x32_bf16(a[mi], b[ni], acc[mi][ni], 0, 0, 0);
        }
    }
#pragma unroll
    for (int mi = 0; mi < 2; ++mi) {
#pragma unroll
        for (int ni = 0; ni < 2; ++ni) {
            const int col = n0 + wcol + ni * 16 + lr;
            const float bv = bias[col];
            if (MODE == 0) {
#pragma unroll
                for (int j = 0; j < 4; ++j) {
                    int row = m0 + wrow + mi * 16 + (lg << 2) + j;
                    ((bf16_t*)out)[(size_t)row * DMODEL + col] = (bf16_t)((acc[mi][ni][j] + bv) * scale);
                }
            } else if (MODE == 1) {
                int row0 = m0 + wrow + mi * 16 + (lg << 2);
                int b = row0 >> 11, key = row0 & (SEQ - 1);
                int h = col >> 6, d = col & 63;
                bf16x4 r;
#pragma unroll
                for (int j = 0; j < 4; ++j) r[j] = (bf16_t)(acc[mi][ni][j] + bv);
                *(bf16x4*)((bf16_t*)out + ((size_t)(b * HEADS + h) * HDIM + d) * SEQ + key) = r;
            } else {
#pragma unroll
                for (int j = 0; j < 4; ++j) {
                    int row = m0 + wrow + mi * 16 + (lg << 2) + j;
                    float x = acc[mi][ni][j] + bv;
                    ((bf16_t*)out)[(size_t)row * DMODEL + col] = (bf16_t)(1.0f / (1.0f + __expf(-x)));
                }
            }
        }
    }
}

// ---------------------------------------------------------------------------
// K2: flash attention (pure softmax(QK^T)@V part; bias term handled by K2b)
// block = (b, h, qtile of 64). 4 waves x 16 q-rows. k-tiles of 64.
// grid: qt(32) x bh(32) with bh fastest => each XCD L2 holds 4 K/V slabs (2MB).
// ---------------------------------------------------------------------------
__global__ __launch_bounds__(256) void attn_kernel(
    const bf16_t* __restrict__ wq, const bf16_t* __restrict__ wk,
    const bf16_t* __restrict__ wvt, bf16_t* __restrict__ attn_o)
{
    __shared__ __align__(16) char smK[8192];
    __shared__ __align__(16) char smV[8192];
    __shared__ __align__(16) char smP[8192];
    const int tid = threadIdx.x;
    const int lane = tid & 63, w = tid >> 6;
    const int bh = blockIdx.x & 31;
    const int qt = blockIdx.x >> 5;
    const int b = bh >> 3, h = bh & 7;
    const int q0 = qt << 6;
    const int lr = lane & 15, lg = lane >> 4;

    // Q fragments in registers (rows w*16 .. +16 of this q-tile)
    bf16x8 qf[2];
    {
        int row = q0 + w * 16 + lr;
        const bf16_t* p = wq + (size_t)(b * SEQ + row) * DMODEL + h * HDIM + lg * 8;
        qf[0] = *(const bf16x8*)(p);
        qf[1] = *(const bf16x8*)(p + 32);
    }
    float mrun[4], lrun[4];
#pragma unroll
    for (int j = 0; j < 4; ++j) { mrun[j] = -1e30f; lrun[j] = 0.f; }
    f32x4 oacc[4] = {};

    for (int kt = 0; kt < SEQ / 64; ++kt) {
        const int k0 = kt * 64;
        __syncthreads();
#pragma unroll
        for (int i = 0; i < 2; ++i) {
            int f = tid + i * 256;
            int row = f >> 3, c16 = f & 7;
            uint4 vk = *(const uint4*)(wk + (size_t)(b * SEQ + k0 + row) * DMODEL + h * HDIM + c16 * 8);
            *(uint4*)(smK + swz(row, c16)) = vk;
            uint4 vv = *(const uint4*)(wvt + ((size_t)(b * HEADS + h) * HDIM + row) * SEQ + k0 + c16 * 8);
            *(uint4*)(smV + swz(row, c16)) = vv;
        }
        __syncthreads();

        // S = Q @ K^T : rows=q (16), cols=keys (64)
        f32x4 s[4] = {};
#pragma unroll
        for (int ks = 0; ks < 2; ++ks) {
#pragma unroll
            for (int nf = 0; nf < 4; ++nf) {
                bf16x8 kbf = *(const bf16x8*)(smK + swz(nf * 16 + lr, lg + ks * 4));
                s[nf] = __builtin_amdgcn_mfma_f32_16x16x32_bf16(qf[ks], kbf, s[nf], 0, 0, 0);
            }
        }
        // online softmax over keys; row j lives in lanes 0..15 of each 16-group
        float mnew[4], sc[4], rs[4];
#pragma unroll
        for (int j = 0; j < 4; ++j) {
            float m = fmaxf(fmaxf(s[0][j], s[1][j]), fmaxf(s[2][j], s[3][j]));
#pragma unroll
            for (int off = 1; off < 16; off <<= 1) m = fmaxf(m, __shfl_xor(m, off));
            mnew[j] = fmaxf(mrun[j], m);
            sc[j] = __expf(mrun[j] - mnew[j]);
            rs[j] = 0.f;
        }
#pragma unroll
        for (int nf = 0; nf < 4; ++nf) {
#pragma unroll
            for (int j = 0; j < 4; ++j) {
                float p = __expf(s[nf][j] - mnew[j]);
                s[nf][j] = p;
                rs[j] += p;
            }
        }
#pragma unroll
        for (int j = 0; j < 4; ++j) {
#pragma unroll
            for (int off = 1; off < 16; off <<= 1) rs[j] += __shfl_xor(rs[j], off);
            lrun[j] = lrun[j] * sc[j] + rs[j];
            mrun[j] = mnew[j];
        }
#pragma unroll
        for (int nf = 0; nf < 4; ++nf)
#pragma unroll
            for (int j = 0; j < 4; ++j) oacc[nf][j] *= sc[j];

        // P -> per-wave LDS (bf16, swizzled); wave-private, no barrier needed
        char* pbase = smP + w * 2048;
#pragma unroll
        for (int nf = 0; nf < 4; ++nf) {
            int col = nf * 16 + lr;
#pragma unroll
            for (int j = 0; j < 4; ++j) {
                int row = lg * 4 + j;
                *(bf16_t*)(pbase + swz(row, col >> 3) + ((col & 7) << 1)) = (bf16_t)s[nf][j];
            }
        }
        // O += P @ V
#pragma unroll
        for (int ks = 0; ks < 2; ++ks) {
            bf16x8 pa = *(const bf16x8*)(pbase + swz(lr, lg + ks * 4));
#pragma unroll
            for (int nf = 0; nf < 4; ++nf) {
                bf16x8 vb = *(const bf16x8*)(smV + swz(nf * 16 + lr, lg + ks * 4));
                oacc[nf] = __builtin_amdgcn_mfma_f32_16x16x32_bf16(pa, vb, oacc[nf], 0, 0, 0);
            }
        }
    }
    float rinv[4];
#pragma unroll
    for (int j = 0; j < 4; ++j) rinv[j] = 1.0f / lrun[j];
#pragma unroll
    for (int nf = 0; nf < 4; ++nf) {
        int col = h * HDIM + nf * 16 + lr;
#pragma unroll
        for (int j = 0; j < 4; ++j) {
            int row = q0 + w * 16 + lg * 4 + j;
            attn_o[(size_t)(b * SEQ + row) * DMODEL + col] = (bf16_t)(oacc[nf][j] * rinv[j]);
        }
    }
}

// ---------------------------------------------------------------------------
// K2b: Bv = bias @ wv   (batched: M=2048, N=512, K=2048)
// tiles 128x128, BK=64, 8 waves (512 thr), grid 4*16*4 = 256
// ---------------------------------------------------------------------------
__global__ __launch_bounds__(512) void biasv_gemm(
    const float* __restrict__ bias, const bf16_t* __restrict__ wvt,
    float* __restrict__ Bv)
{
    __shared__ __align__(16) char smA[16384];
    __shared__ __align__(16) char smB[16384];
    const int tid = threadIdx.x;
    const int lane = tid & 63, w = tid >> 6;
    const int nt = blockIdx.x & 3;
    const int mt = (blockIdx.x >> 2) & 15;
    const int b = blockIdx.x >> 6;
    const int m0 = mt << 7, n0 = nt << 7;
    const int wr = w >> 2, wc = w & 3;
    const int lr = lane & 15, lg = lane >> 4;

    f32x4 acc[4][2] = {};
    for (int kb = 0; kb < SEQ / 64; ++kb) {
        const int k0 = kb * 64;
        __syncthreads();
#pragma unroll
        for (int i = 0; i < 4; ++i) {
            int f = tid + i * 512;
            int row = f >> 4, c4 = f & 15;
            float4 v = *(const float4*)(bias + ((size_t)b * SEQ + m0 + row) * SEQ + k0 + c4 * 4);
            *(bf16x4*)(smA + swz(row, c4 >> 1) + ((c4 & 1) << 3)) = cvt4(v);
        }
#pragma unroll
        for (int i = 0; i < 2; ++i) {
            int f = tid + i * 512;
            int row = f >> 3, c16 = f & 7;
            int n = n0 + row;
            uint4 v = *(const uint4*)(wvt + ((size_t)(b * HEADS + (n >> 6)) * HDIM + (n & 63)) * SEQ + k0 + c16 * 8);
            *(uint4*)(smB + swz(row, c16)) = v;
        }
        __syncthreads();
#pragma unroll
        for (int ks = 0; ks < 2; ++ks) {
            bf16x8 a[4], bb[2];
#pragma unroll
            for (int mi = 0; mi < 4; ++mi)
                a[mi] = *(const bf16x8*)(smA + swz(wr * 64 + mi * 16 + lr, lg + ks * 4));
#pragma unroll
            for (int ni = 0; ni < 2; ++ni)
                bb[ni] = *(const bf16x8*)(smB + swz(wc * 32 + ni * 16 + lr, lg + ks * 4));
#pragma unroll
            for (int mi = 0; mi < 4; ++mi)
#pragma unroll
                for (int ni = 0; ni < 2; ++ni)
                    acc[mi][ni] = __builtin_amdgcn_mfma_f32_16x16x32_bf16(a[mi], bb[ni], acc[mi][ni], 0, 0, 0);
        }
    }
#pragma unroll
    for (int mi = 0; mi < 4; ++mi) {
#pragma unroll
        for (int ni = 0; ni < 2; ++ni) {
            int col = n0 + wc * 32 + ni * 16 + lr;
#pragma unroll
            for (int j = 0; j < 4; ++j) {
                int row = m0 + wr * 64 + mi * 16 + lg * 4 + j;
                Bv[((size_t)b * SEQ + row) * DMODEL + col] = acc[mi][ni][j];
            }
        }
    }
}

// ---------------------------------------------------------------------------
// K3: out = (g * (attn + Bv)) @ Wo + bo    (M=8192, N=512, K=512)
// attn/g are bf16, Bv fp32; fused A staging; fp32 output
// ---------------------------------------------------------------------------
__global__ __launch_bounds__(256) void out_gemm(
    const bf16_t* __restrict__ atn, const float* __restrict__ Bvp,
    const bf16_t* __restrict__ gg, const bf16_t* __restrict__ Wot,
    const float* __restrict__ bo, float* __restrict__ out)
{
    __shared__ __align__(16) char smA[8192];
    __shared__ __align__(16) char smB[8192];
    const int tid = threadIdx.x;
    const int lane = tid & 63, w = tid >> 6;
    const int m0 = (blockIdx.x >> 3) << 6;
    const int n0 = (blockIdx.x & 7) << 6;
    const int wrow = (w >> 1) * 32, wcol = (w & 1) * 32;
    const int lr = lane & 15, lg = lane >> 4;

    f32x4 acc[2][2] = {};
    for (int kb = 0; kb < 8; ++kb) {
        const int k0 = kb * 64;
        __syncthreads();
#pragma unroll
        for (int i = 0; i < 4; ++i) {
            int f = tid + i * 256;
            int row = f >> 4, c4 = f & 15;
            size_t idx = (size_t)(m0 + row) * DMODEL + k0 + c4 * 4;
            bf16x4 a4 = *(const bf16x4*)(atn + idx);
            bf16x4 g4 = *(const bf16x4*)(gg + idx);
            float4 b4 = *(const float4*)(Bvp + idx);
            bf16x4 r;
            r[0] = (bf16_t)((float)g4[0] * ((float)a4[0] + b4.x));
            r[1] = (bf16_t)((float)g4[1] * ((float)a4[1] + b4.y));
            r[2] = (bf16_t)((float)g4[2] * ((float)a4[2] + b4.z));
            r[3] = (bf16_t)((float)g4[3] * ((float)a4[3] + b4.w));
            *(bf16x4*)(smA + swz(row, c4 >> 1) + ((c4 & 1) << 3)) = r;
        }
#pragma unroll
        for (int i = 0; i < 2; ++i) {
            int f = tid + i * 256;
            int row = f >> 3, c16 = f & 7;
            uint4 v = *(const uint4*)(Wot + (size_t)(n0 + row) * DMODEL + k0 + c16 * 8);
            *(uint4*)(smB + swz(row, c16)) = v;
        }
        __syncthreads();
#pragma unroll
        for (int ks = 0; ks < 2; ++ks) {
            bf16x8 a[2], b[2];
#pragma unroll
            for (int mi = 0; mi < 2; ++mi)
                a[mi] = *(const bf16x8*)(smA + swz(wrow + mi * 16 + lr, lg + ks * 4));
#pragma unroll
            for (int ni = 0; ni < 2; ++ni)
                b[ni] = *(const bf16x8*)(smB + swz(wcol + ni * 16 + lr, lg + ks * 4));
#pragma unroll
            for (int mi = 0; mi < 2; ++mi)
#pragma unroll
                for (int ni = 0; ni < 2; ++ni)
                    acc[mi][ni] = __builtin_amdgcn_mfma_f32_16x16x32_bf16(a[mi], b[ni], acc[mi][ni], 0, 0, 0);
        }
    }
#pragma unroll
    for (int mi = 0; mi < 2; ++mi) {
#pragma unroll
        for (int ni = 0; ni < 2; ++ni) {
            int col = n0 + wcol + ni * 16 + lr;
            float bb = bo[col];
#pragma unroll
            for (int j = 0; j < 4; ++j) {
                int row = m0 + wrow + mi * 16 + (lg << 2) + j;
                out[(size_t)row * DMODEL + col] = acc[mi][ni][j] + bb;
            }
        }
    }
}

// ---------------------------------------------------------------------------
extern "C" void kernel_launch(void* const* d_in, const int* in_sizes, int n_in,
                              void* d_out, int out_size, void* d_ws, size_t ws_size,
                              hipStream_t stream)
{
    const float* q    = (const float*)d_in[0];
    const float* k    = (const float*)d_in[1];
    const float* v    = (const float*)d_in[2];
    const float* bias = (const float*)d_in[3];
    const float* Wq   = (const float*)d_in[4];
    const float* bq   = (const float*)d_in[5];
    const float* Wk   = (const float*)d_in[6];
    const float* bk   = (const float*)d_in[7];
    const float* Wv   = (const float*)d_in[8];
    const float* bv   = (const float*)d_in[9];
    const float* Wg   = (const float*)d_in[10];
    const float* bg   = (const float*)d_in[11];
    const float* Wo   = (const float*)d_in[12];
    const float* bo   = (const float*)d_in[13];
    float* out = (float*)d_out;

    char* ws = (char*)d_ws;
    const size_t WSZ = (size_t)DMODEL * DMODEL;          // 262144 elems
    const size_t TOK = (size_t)NB * SEQ * DMODEL;        // 4.19M elems
    bf16_t* Wt   = (bf16_t*)ws;                          // 5 matrices, bf16 [n][k]
    bf16_t* wq_  = (bf16_t*)(ws + 5 * WSZ * 2);          // (B,Q,512) bf16, scaled
    bf16_t* wk_  = wq_ + TOK;                            // (B,K,512) bf16
    bf16_t* wvt  = wk_ + TOK;                            // (B,H,64,K) bf16
    bf16_t* atn  = wvt + TOK;                            // (B,Q,512) bf16
    bf16_t* g_   = atn + TOK;                            // (B,Q,512) bf16
    float*  Bv_  = (float*)(g_ + TOK);                   // (B,Q,512) f32
    // total ws use: 2.6MB + 5*8MB + 16MB = ~58.6 MB

    prep_weights<<<320, 256, 0, stream>>>(Wq, Wk, Wv, Wg, Wo, Wt);
    gemm_proj<0><<<1024, 256, 0, stream>>>(q, Wt,            bq, (void*)wq_, QKSCALE);
    gemm_proj<0><<<1024, 256, 0, stream>>>(k, Wt + WSZ,      bk, (void*)wk_, 1.0f);
    gemm_proj<1><<<1024, 256, 0, stream>>>(v, Wt + 2 * WSZ,  bv, (void*)wvt, 1.0f);
    gemm_proj<2><<<1024, 256, 0, stream>>>(q, Wt + 3 * WSZ,  bg, (void*)g_,  1.0f);
    attn_kernel<<<1024, 256, 0, stream>>>(wq_, wk_, wvt, atn);
    biasv_gemm<<<256, 512, 0, stream>>>(bias, wvt, Bv_);
    out_gemm<<<1024, 256, 0, stream>>>(atn, Bv_, g_, Wt + 4 * WSZ, bo, out);
}